// Round 12
// baseline (1511.257 us; speedup 1.0000x reference)
//
#include <hip/hip_runtime.h>
#include <hip/hip_bf16.h>
#include <math.h>

#define RSQ 0.99999500003749969f   // 1/sqrt(1+1e-5)
#define SLOPE 0.01f

typedef __attribute__((ext_vector_type(8))) short short8;
typedef __attribute__((ext_vector_type(4))) float f32x4;

__device__ __forceinline__ float sigmoidf_(float x){ return 1.0f/(1.0f+expf(-x)); }

__device__ __forceinline__ unsigned short f2bf(float f){
    unsigned u = __float_as_uint(f);
    u += 0x7fff + ((u >> 16) & 1);      // RNE
    return (unsigned short)(u >> 16);
}
__device__ __forceinline__ float bf2f(unsigned short s){
    return __uint_as_float(((unsigned)s) << 16);
}

// async global->LDS, 16B per lane
__device__ __forceinline__ void stage16(const unsigned short* g, unsigned short* l) {
    __builtin_amdgcn_global_load_lds(
        (const __attribute__((address_space(1))) unsigned int*)g,
        (__attribute__((address_space(3))) unsigned int*)l, 16, 0, 0);
}

// ---------------- mask: prod_k cos(fW*rng + fB) ----------------
__global__ void mask_partial_kernel(const float* __restrict__ fW, const float* __restrict__ fB,
                                    float* __restrict__ partial)
{
    int p = blockIdx.x*256 + threadIdx.x;   // 0..15902
    if (p >= 15903) return;
    int w = p % 513;
    float r = (float)(w + 1);
    int k0 = blockIdx.y * 32;
    float prod = 1.0f;
    for (int k = k0; k < k0 + 32; ++k) {
        float a = fW[(size_t)k*15903 + p] * r + fB[(size_t)k*15903 + p];
        prod *= cosf(a);
    }
    partial[blockIdx.y*15903 + p] = prod;
}

__global__ void mask_finalize_apply(const float* __restrict__ partial, const float* __restrict__ x,
                                    float* __restrict__ xm)
{
    int p = blockIdx.x*256 + threadIdx.x;
    if (p >= 15903) return;
    float m = 1.0f;
    #pragma unroll
    for (int c = 0; c < 32; ++c) m *= partial[c*15903 + p];
    for (int n = 0; n < 32; ++n)
        xm[(size_t)n*15903 + p] = x[(size_t)n*15903 + p] * m;
}

// ---------------- weight transforms ----------------
__global__ void wtrans9_kernel(const float* __restrict__ w, unsigned short* __restrict__ o,
                               int Cout, int Cin)
{
    int idx = blockIdx.x*256 + threadIdx.x;
    int cc = Cout*Cin;
    if (idx >= 9*cc) return;
    int tap = idx / cc;
    int r = idx - tap*cc;
    int co = r / Cin, ci = r - co*Cin;
    int kh = tap/3, kw = tap - kh*3;
    o[idx] = f2bf(w[((size_t)(co*Cin + ci)*3 + kh)*3 + kw]);
}
__global__ void wtrans1_kernel(const float* __restrict__ w, unsigned short* __restrict__ o, int total)
{
    int idx = blockIdx.x*256 + threadIdx.x;
    if (idx < total) o[idx] = f2bf(w[idx]);
}

// whh (1024,256) fp32 -> MFMA-fragment-contiguous bf16
__global__ void whh_frag_kernel(const float* __restrict__ whh, unsigned short* __restrict__ out)
{
    int tid = blockIdx.x*256 + threadIdx.x;  // 262144 exact
    int e    = tid & 7;
    int lane = (tid >> 3) & 63;
    int kc   = (tid >> 9) & 7;
    int u0   = (tid >> 12) & 15;
    int g    = tid >> 16;
    int j = (g << 8) + (u0 << 4) + (lane & 15);
    int k = (kc << 5) + ((lane >> 4) << 3) + e;
    out[tid] = f2bf(whh[(size_t)j*256 + k]);
}

// ---------------- conv1: Cin=1 direct, fp32 in -> bf16 NHWC (rows 1..31 of [33][515][64]) ----------------
__launch_bounds__(256)
__global__ void conv1_kernel(const float* __restrict__ xm, const float* __restrict__ w1,
                             const float* __restrict__ g, const float* __restrict__ b,
                             unsigned short* __restrict__ O)
{
    __shared__ float wl[576];
    __shared__ float sg[64], sb[64];
    int tid = threadIdx.x;
    if (tid < 64) { sg[tid] = g[tid]*RSQ; sb[tid] = b[tid]; }
    for (int i = tid; i < 576; i += 256) wl[i] = w1[i];
    __syncthreads();
    int px = blockIdx.x*256 + tid;
    int n = blockIdx.z;
    if (px >= 15903) return;
    int h = px / 513, w = px - h*513;
    const float* xp = xm + (size_t)n*15903;
    float v[9];
    #pragma unroll
    for (int dh = 0; dh < 3; ++dh)
      #pragma unroll
      for (int dw = 0; dw < 3; ++dw) {
        int hh = h+dh-1, ww = w+dw-1;
        bool ok = ((unsigned)hh < 31u) && ((unsigned)ww < 513u);
        v[dh*3+dw] = ok ? xp[hh*513 + ww] : 0.f;
      }
    unsigned short* op = O + (((size_t)(n*33 + h + 1))*515 + (w + 1))*64;
    #pragma unroll
    for (int c8 = 0; c8 < 8; ++c8) {
        unsigned tmp[8];
        #pragma unroll
        for (int j = 0; j < 8; ++j) {
            int co = c8*8 + j;
            const float* wr = &wl[co*9];
            float a = 0.f;
            #pragma unroll
            for (int t2 = 0; t2 < 9; ++t2) a += wr[t2]*v[t2];
            a = a*sg[co] + sb[co];
            a = (a >= 0.f) ? a : SLOPE*a;
            tmp[j] = f2bf(a);
        }
        uint4 pk;
        pk.x = tmp[0] | (tmp[1]<<16);
        pk.y = tmp[2] | (tmp[3]<<16);
        pk.z = tmp[4] | (tmp[5]<<16);
        pk.w = tmp[6] | (tmp[7]<<16);
        *(uint4*)(op + c8*8) = pk;
    }
}

// ---------------- LDS-staged implicit-GEMM 3x3 conv (+1x1 shortcut) via MFMA ----------------
// Wave roles: cg2 = wave>>1 picks co-half (32 co), th = wave&1 picks px-half.
// Each B-fragment read feeds 2 MFMAs (both co-groups). POOL=1 fuses bn+lrelu+maxpool4.
template<int CIN, int TPX, int CS, int POOL>
__launch_bounds__(256, 2)
__global__ void conv_lds_kernel(const unsigned short* __restrict__ X,
                                const unsigned short* __restrict__ W9,
                                const unsigned short* __restrict__ Xs,
                                const unsigned short* __restrict__ Ws,
                                unsigned short* __restrict__ O,
                                int Wp, int WT, int WpS,
                                int HO, int HOFF, int WpO, int OOFF, int Cout,
                                const float* __restrict__ g, const float* __restrict__ b)
{
    constexpr int KQ  = CIN/8;
    constexpr int PXT = TPX*16 + 2;
    constexpr int UX  = 3*PXT*KQ;
    constexpr int KQS = (CS > 0) ? CS/8 : 8;
    constexpr int US  = (CS > 0) ? TPX*16*KQS : 0;
    constexpr int UT  = UX + US;
    constexpr int NU  = (UT + 255)/256;
    constexpr int NKC = CIN/32;
    constexpr int TPXH = TPX/2;
    __shared__ uint4 lds4[UT + 8];

    const int tid = threadIdx.x;
    const int lane = tid & 63;
    const int wave = tid >> 6;
    const int cg2 = wave >> 1;
    const int th  = wave & 1;
    const int n  = blockIdx.z;
    const int wt = blockIdx.x % WT;
    const int h  = blockIdx.x / WT;
    const int w0 = wt*(TPX*16);
    const int l15 = lane & 15;
    const int gq  = lane >> 4;
    const int cwb = blockIdx.y*64 + cg2*32;

    // ---- stage ----
    uint4 tmp[NU];
    #pragma unroll
    for (int i = 0; i < NU; ++i) {
        int u = tid + i*256;
        if (u < UX) {
            int r   = u / (PXT*KQ);
            int rem = u - r*(PXT*KQ);
            int px  = rem / KQ;
            int kq  = rem - px*KQ;
            tmp[i] = *(const uint4*)(X + (((size_t)(n*33 + h + r))*Wp + w0 + px)*CIN + kq*8);
        } else if (CS > 0 && u < UT) {
            int us = u - UX;
            int px = us / KQS;
            int kq = us - px*KQS;
            tmp[i] = *(const uint4*)(Xs + (((size_t)(n*33 + h + 1))*WpS + w0 + 1 + px)*CS + kq*8);
        }
    }
    #pragma unroll
    for (int i = 0; i < NU; ++i) {
        int u = tid + i*256;
        if (u < UT) {
            int px;
            if (u < UX) { int rem = u % (PXT*KQ); px = rem / KQ; }
            else        { px = (u - UX) / KQS; }
            *(uint4*)((char*)lds4 + ((u*16) ^ ((px & 7) << 4))) = tmp[i];
        }
    }
    __syncthreads();

    // ---- compute ----
    f32x4 acc0[TPXH] = {};
    f32x4 acc1[TPXH] = {};
    #pragma unroll
    for (int dh = 0; dh < 3; ++dh) {
        #pragma unroll
        for (int dw = 0; dw < 3; ++dw) {
            short8 a0[NKC], a1[NKC];
            #pragma unroll
            for (int kc = 0; kc < NKC; ++kc) {
                a0[kc] = *(const short8*)(W9 + ((size_t)((dh*3+dw)*Cout + cwb + l15))*CIN + kc*32 + gq*8);
                a1[kc] = *(const short8*)(W9 + ((size_t)((dh*3+dw)*Cout + cwb + 16 + l15))*CIN + kc*32 + gq*8);
            }
            #pragma unroll
            for (int kc = 0; kc < NKC; ++kc) {
                #pragma unroll
                for (int t = 0; t < TPXH; ++t) {
                    int px = dw + (th*TPXH + t)*16 + l15;
                    int u  = (dh*PXT + px)*KQ + kc*4 + gq;
                    short8 bv = *(const short8*)((const char*)lds4 + ((u*16) ^ ((px & 7) << 4)));
                    acc0[t] = __builtin_amdgcn_mfma_f32_16x16x32_bf16(a0[kc], bv, acc0[t], 0, 0, 0);
                    acc1[t] = __builtin_amdgcn_mfma_f32_16x16x32_bf16(a1[kc], bv, acc1[t], 0, 0, 0);
                }
            }
        }
    }

    if (CS > 0) {
        #pragma unroll
        for (int kc = 0; kc < KQS/4; ++kc) {
            short8 a0 = *(const short8*)(Ws + (size_t)(cwb + l15)*CS + kc*32 + gq*8);
            short8 a1 = *(const short8*)(Ws + (size_t)(cwb + 16 + l15)*CS + kc*32 + gq*8);
            #pragma unroll
            for (int t = 0; t < TPXH; ++t) {
                int px = (th*TPXH + t)*16 + l15;
                int u  = UX + px*KQS + kc*4 + gq;
                short8 bv = *(const short8*)((const char*)lds4 + ((u*16) ^ ((px & 7) << 4)));
                acc0[t] = __builtin_amdgcn_mfma_f32_16x16x32_bf16(a0, bv, acc0[t], 0, 0, 0);
                acc1[t] = __builtin_amdgcn_mfma_f32_16x16x32_bf16(a1, bv, acc1[t], 0, 0, 0);
            }
        }
    }

    // ---- epilogue (per co-group, static unroll) ----
#define EPIG(ACC, G) do { \
    int cb = cwb + (G)*16 + gq*4; \
    float s0 = g[cb+0]*RSQ, s1 = g[cb+1]*RSQ, s2 = g[cb+2]*RSQ, s3 = g[cb+3]*RSQ; \
    float o0 = b[cb+0], o1 = b[cb+1], o2 = b[cb+2], o3 = b[cb+3]; \
    _Pragma("unroll") \
    for (int t = 0; t < TPXH; ++t) { \
        float v0 = ACC[t][0]*s0 + o0; v0 = (v0 >= 0.f) ? v0 : SLOPE*v0; \
        float v1 = ACC[t][1]*s1 + o1; v1 = (v1 >= 0.f) ? v1 : SLOPE*v1; \
        float v2 = ACC[t][2]*s2 + o2; v2 = (v2 >= 0.f) ? v2 : SLOPE*v2; \
        float v3 = ACC[t][3]*s3 + o3; v3 = (v3 >= 0.f) ? v3 : SLOPE*v3; \
        int w = w0 + (th*TPXH + t)*16 + l15; \
        if (POOL) { \
            v0 = fmaxf(v0, __shfl_xor(v0, 1)); v0 = fmaxf(v0, __shfl_xor(v0, 2)); \
            v1 = fmaxf(v1, __shfl_xor(v1, 1)); v1 = fmaxf(v1, __shfl_xor(v1, 2)); \
            v2 = fmaxf(v2, __shfl_xor(v2, 1)); v2 = fmaxf(v2, __shfl_xor(v2, 2)); \
            v3 = fmaxf(v3, __shfl_xor(v3, 1)); v3 = fmaxf(v3, __shfl_xor(v3, 2)); \
            if ((l15 & 3) == 0) { \
                int pw = w >> 2; \
                uint2 pk; \
                pk.x = (unsigned)f2bf(v0) | ((unsigned)f2bf(v1) << 16); \
                pk.y = (unsigned)f2bf(v2) | ((unsigned)f2bf(v3) << 16); \
                *(uint2*)(O + (((size_t)(n*HO + h + HOFF))*WpO + pw + OOFF)*Cout + cb) = pk; \
            } \
        } else { \
            uint2 pk; \
            pk.x = (unsigned)f2bf(v0) | ((unsigned)f2bf(v1) << 16); \
            pk.y = (unsigned)f2bf(v2) | ((unsigned)f2bf(v3) << 16); \
            *(uint2*)(O + (((size_t)(n*HO + h + HOFF))*WpO + w + OOFF)*Cout + cb) = pk; \
        } \
    } \
} while(0)
    EPIG(acc0, 0);
    EPIG(acc1, 1);
#undef EPIG
}

// ---------------- W=8 LDS-staged conv for r3 layers ----------------
// Inputs padded [34][10][C]. Block = (h-pair, 128co, n); wave = 32 co x 16 px (2 rows x 8).
// POOL=1: fuse bn+lrelu+maxpool(8->2), write XP4-style [n][31][2][Cout].
template<int CIN, int CS, int POOL>
__launch_bounds__(256, 2)
__global__ void conv_w8_kernel(const unsigned short* __restrict__ X,
                               const unsigned short* __restrict__ W9,
                               const unsigned short* __restrict__ Xs,
                               const unsigned short* __restrict__ Ws,
                               unsigned short* __restrict__ O, int Cout,
                               const float* __restrict__ g, const float* __restrict__ b)
{
    constexpr int KQ  = CIN/8;
    constexpr int UX  = 4*10*KQ;
    constexpr int KQS = (CS > 0) ? CS/8 : 8;
    constexpr int US  = (CS > 0) ? 2*8*KQS : 0;
    constexpr int UT  = UX + US;
    constexpr int NU  = (UT + 255)/256;
    constexpr int NKC = CIN/32;
    __shared__ uint4 lds4[UT + 8];

    const int tid = threadIdx.x;
    const int lane = tid & 63;
    const int wave = tid >> 6;
    const int hp = blockIdx.x;          // 0..15
    const int n  = blockIdx.z;
    const int h0 = hp*2;
    const int l15 = lane & 15;
    const int gq  = lane >> 4;
    const int r = l15 >> 3;
    const int w = l15 & 7;
    const int cwb = blockIdx.y*128 + wave*32;

    uint4 tmp[NU];
    #pragma unroll
    for (int i = 0; i < NU; ++i) {
        int u = tid + i*256;
        if (u < UX) {
            int row = u / (10*KQ);
            int rem = u - row*(10*KQ);
            int px  = rem / KQ;
            int kq  = rem - px*KQ;
            tmp[i] = *(const uint4*)(X + (((size_t)(n*34 + h0 + row))*10 + px)*CIN + kq*8);
        } else if (CS > 0 && u < UT) {
            int us = u - UX;
            int rs = us / (8*KQS);
            int rem = us - rs*(8*KQS);
            int px8 = rem / KQS;
            int kq  = rem - px8*KQS;
            tmp[i] = *(const uint4*)(Xs + (((size_t)(n*34 + h0 + 1 + rs))*10 + px8 + 1)*CS + kq*8);
        }
    }
    #pragma unroll
    for (int i = 0; i < NU; ++i) {
        int u = tid + i*256;
        if (u < UT) {
            int key;
            if (u < UX) { int rem = u % (10*KQ); key = rem / KQ; }
            else        { key = ((u - UX) % (8*KQS)) / KQS; }
            *(uint4*)((char*)lds4 + ((u*16) ^ ((key & 7) << 4))) = tmp[i];
        }
    }
    __syncthreads();

    f32x4 acc0 = {0,0,0,0}, acc1 = {0,0,0,0};
    #pragma unroll
    for (int dh = 0; dh < 3; ++dh) {
        #pragma unroll
        for (int dw = 0; dw < 3; ++dw) {
            short8 a0[NKC], a1[NKC];
            #pragma unroll
            for (int kc = 0; kc < NKC; ++kc) {
                a0[kc] = *(const short8*)(W9 + ((size_t)((dh*3+dw)*Cout + cwb + l15))*CIN + kc*32 + gq*8);
                a1[kc] = *(const short8*)(W9 + ((size_t)((dh*3+dw)*Cout + cwb + 16 + l15))*CIN + kc*32 + gq*8);
            }
            #pragma unroll
            for (int kc = 0; kc < NKC; ++kc) {
                int row_s = r + dh;
                int col = w + dw;
                int u = (row_s*10 + col)*KQ + kc*4 + gq;
                short8 bv = *(const short8*)((const char*)lds4 + ((u*16) ^ ((col & 7) << 4)));
                acc0 = __builtin_amdgcn_mfma_f32_16x16x32_bf16(a0[kc], bv, acc0, 0, 0, 0);
                acc1 = __builtin_amdgcn_mfma_f32_16x16x32_bf16(a1[kc], bv, acc1, 0, 0, 0);
            }
        }
    }

    if (CS > 0) {
        #pragma unroll
        for (int kc = 0; kc < KQS/4; ++kc) {
            short8 a0 = *(const short8*)(Ws + (size_t)(cwb + l15)*CS + kc*32 + gq*8);
            short8 a1 = *(const short8*)(Ws + (size_t)(cwb + 16 + l15)*CS + kc*32 + gq*8);
            int u = UX + (r*8 + w)*KQS + kc*4 + gq;
            short8 bv = *(const short8*)((const char*)lds4 + ((u*16) ^ ((w & 7) << 4)));
            acc0 = __builtin_amdgcn_mfma_f32_16x16x32_bf16(a0, bv, acc0, 0, 0, 0);
            acc1 = __builtin_amdgcn_mfma_f32_16x16x32_bf16(a1, bv, acc1, 0, 0, 0);
        }
    }

    const int hr = h0 + r;
    const bool valid = hr < 31;
#define EPIG8(ACC, G) do { \
    int cb = cwb + (G)*16 + gq*4; \
    float s0 = g[cb+0]*RSQ, s1 = g[cb+1]*RSQ, s2 = g[cb+2]*RSQ, s3 = g[cb+3]*RSQ; \
    float o0 = b[cb+0], o1 = b[cb+1], o2 = b[cb+2], o3 = b[cb+3]; \
    float v0 = ACC[0]*s0 + o0; v0 = (v0 >= 0.f) ? v0 : SLOPE*v0; \
    float v1 = ACC[1]*s1 + o1; v1 = (v1 >= 0.f) ? v1 : SLOPE*v1; \
    float v2 = ACC[2]*s2 + o2; v2 = (v2 >= 0.f) ? v2 : SLOPE*v2; \
    float v3 = ACC[3]*s3 + o3; v3 = (v3 >= 0.f) ? v3 : SLOPE*v3; \
    if (POOL) { \
        v0 = fmaxf(v0, __shfl_xor(v0, 1)); v0 = fmaxf(v0, __shfl_xor(v0, 2)); \
        v1 = fmaxf(v1, __shfl_xor(v1, 1)); v1 = fmaxf(v1, __shfl_xor(v1, 2)); \
        v2 = fmaxf(v2, __shfl_xor(v2, 1)); v2 = fmaxf(v2, __shfl_xor(v2, 2)); \
        v3 = fmaxf(v3, __shfl_xor(v3, 1)); v3 = fmaxf(v3, __shfl_xor(v3, 2)); \
        if (((l15 & 3) == 0) && valid) { \
            uint2 pk; \
            pk.x = (unsigned)f2bf(v0) | ((unsigned)f2bf(v1) << 16); \
            pk.y = (unsigned)f2bf(v2) | ((unsigned)f2bf(v3) << 16); \
            *(uint2*)(O + (((size_t)(n*31 + hr))*2 + (w >> 2))*Cout + cb) = pk; \
        } \
    } else if (valid) { \
        uint2 pk; \
        pk.x = (unsigned)f2bf(v0) | ((unsigned)f2bf(v1) << 16); \
        pk.y = (unsigned)f2bf(v2) | ((unsigned)f2bf(v3) << 16); \
        *(uint2*)(O + (((size_t)(n*34 + hr + 1))*10 + w + 1)*Cout + cb) = pk; \
    } \
} while(0)
    EPIG8(acc0, 0);
    EPIG8(acc1, 1);
#undef EPIG8
}

// ---------------- feats: [n][31][2][256] bf16 NHWC -> [n][31][512] fp32 ----------------
__global__ void feats_kernel(const unsigned short* __restrict__ p4, float* __restrict__ fe)
{
    int idx = blockIdx.x*256 + threadIdx.x;   // 507904
    int cw = idx & 511;
    int nh = idx >> 9;
    int c = cw >> 1, w = cw & 1;
    fe[idx] = bf2f(p4[((size_t)nh*2 + w)*256 + c]);
}

// ---------------- tiled SGEMM: C[M,N] = A[M,K] @ B[N,K]^T + bias(+bias2) ----------------
#define GM 32
#define GN 64
#define GK 32
template<int XPOSE>
__launch_bounds__(256)
__global__ void gemm_bias_kernel(const float* __restrict__ A, const float* __restrict__ B,
                                 const float* __restrict__ bias, const float* __restrict__ bias2,
                                 float* __restrict__ C, int M, int N, int K)
{
    __shared__ float As[GM][GK+1];
    __shared__ float Bs[GN][GK+1];
    int m0 = blockIdx.x*GM, n0 = blockIdx.y*GN;
    int tid = threadIdx.x;
    int mi = tid >> 4;
    int ni = (tid & 15) * 4;
    float acc[2][4] = {};

    for (int k0 = 0; k0 < K; k0 += GK) {
        for (int i = tid; i < GM*GK; i += 256) {
            int r = i >> 5, c = i & 31;
            int m = m0 + r;
            As[r][c] = (m < M) ? A[(size_t)m*K + k0 + c] : 0.f;
        }
        for (int i = tid; i < GN*GK; i += 256) {
            int r = i >> 5, c = i & 31;
            int n = n0 + r;
            Bs[r][c] = (n < N) ? B[(size_t)n*K + k0 + c] : 0.f;
        }
        __syncthreads();
        #pragma unroll
        for (int kk = 0; kk < GK; ++kk) {
            float a0 = As[mi][kk], a1 = As[mi+16][kk];
            float b0 = Bs[ni][kk], b1 = Bs[ni+1][kk], b2 = Bs[ni+2][kk], b3 = Bs[ni+3][kk];
            acc[0][0] += a0*b0; acc[0][1] += a0*b1; acc[0][2] += a0*b2; acc[0][3] += a0*b3;
            acc[1][0] += a1*b0; acc[1][1] += a1*b1; acc[1][2] += a1*b2; acc[1][3] += a1*b3;
        }
        __syncthreads();
    }
    #pragma unroll
    for (int r = 0; r < 2; ++r) {
        int m = m0 + mi + r*16;
        if (m >= M) continue;
        #pragma unroll
        for (int q = 0; q < 4; ++q) {
            int n = n0 + ni + q;
            if (n >= N) continue;
            float v = acc[r][q];
            if (bias)  v += bias[n];
            if (bias2) v += bias2[n];
            if (XPOSE) C[((size_t)(m % 31)*32 + (m / 31))*N + n] = v;
            else       C[(size_t)m*N + n] = v;
        }
    }
}

// ---------------- LSTM scan via MFMA + global_load_lds weight pipeline ----------------
__launch_bounds__(1024)
__global__ void lstm_scan_mfma(const float* __restrict__ xpT,
                               const unsigned short* __restrict__ wf,
                               float* __restrict__ hcat)
{
    const int d  = blockIdx.x >> 1;
    const int bh = blockIdx.x & 1;
    const int tid = threadIdx.x;
    const int u0 = tid >> 6;
    const int lane = tid & 63;
    const int l15 = lane & 15;
    const int q = lane >> 4;

    __shared__ unsigned short hbuf[2][4096];          // 16 KB
    __shared__ unsigned short wst[16][2][2048];       // 128 KB

    ((int4*)hbuf)[tid & 1023] = make_int4(0,0,0,0);

    const unsigned short* wfd = wf + (size_t)d*262144;
    const float* xpd = xpT + (size_t)d*992*1024 + (size_t)bh*16*1024;
    const unsigned short* wsrc = wfd + (size_t)u0*4096 + (size_t)lane*8;
    unsigned short* wl = &wst[u0][0][0];

#define STAGE(KC, PB) do { \
    unsigned short* dst_ = wl + (PB)*2048; \
    stage16(wsrc + 0*65536 + (KC)*512, dst_ + 0*512); \
    stage16(wsrc + 1*65536 + (KC)*512, dst_ + 1*512); \
    stage16(wsrc + 2*65536 + (KC)*512, dst_ + 2*512); \
    stage16(wsrc + 3*65536 + (KC)*512, dst_ + 3*512); \
} while(0)

    STAGE(0, 0);
    __syncthreads();

    float c0=0.f, c1=0.f, c2=0.f, c3=0.f;
    const int ubase = u0*16 + q*4;
    const int rb = l15*512 + q*16;
    const int xr = (l15&7)<<4;

#define HRD(kc)   (*(const short8*)(hb + ((rb + (kc)*64) ^ xr)))
#define MF(w_,h_,a_) a_ = __builtin_amdgcn_mfma_f32_16x16x32_bf16(w_, h_, a_, 0, 0, 0)

    for (int s = 0; s < 31; ++s) {
        const int t = d ? (30 - s) : s;
        const int cur = s & 1, nxt = cur ^ 1;
        const float* xb = xpd + (size_t)t*32768 + (size_t)l15*1024;
        float4 xi = *(const float4*)(xb + ubase);
        float4 xf = *(const float4*)(xb + 256 + ubase);
        float4 xg = *(const float4*)(xb + 512 + ubase);
        float4 xo = *(const float4*)(xb + 768 + ubase);

        const char* hb = (const char*)hbuf[cur];
        f32x4 a0={0,0,0,0}, a1={0,0,0,0}, a2={0,0,0,0}, a3={0,0,0,0};

        #pragma unroll
        for (int kc = 0; kc < 8; ++kc) {
            if (kc < 7) STAGE(kc+1, (kc+1)&1);
            else        STAGE(0, 0);
            if (kc == 0) asm volatile("s_waitcnt vmcnt(8)" ::: "memory");
            else         asm volatile("s_waitcnt vmcnt(4)" ::: "memory");
            const unsigned short* wb = wl + (kc&1)*2048;
            short8 w0 = *(const short8*)(wb + 0*512 + lane*8);
            short8 w1 = *(const short8*)(wb + 1*512 + lane*8);
            short8 w2 = *(const short8*)(wb + 2*512 + lane*8);
            short8 w3 = *(const short8*)(wb + 3*512 + lane*8);
            short8 h = HRD(kc);
            MF(w0,h,a0); MF(w1,h,a1); MF(w2,h,a2); MF(w3,h,a3);
        }

        float hv0, hv1, hv2, hv3;
        { float gi=a0[0]+xi.x, gf=a1[0]+xf.x, gg=a2[0]+xg.x, go=a3[0]+xo.x;
          float cn = sigmoidf_(gf)*c0 + sigmoidf_(gi)*tanhf(gg); c0 = cn; hv0 = sigmoidf_(go)*tanhf(cn); }
        { float gi=a0[1]+xi.y, gf=a1[1]+xf.y, gg=a2[1]+xg.y, go=a3[1]+xo.y;
          float cn = sigmoidf_(gf)*c1 + sigmoidf_(gi)*tanhf(gg); c1 = cn; hv1 = sigmoidf_(go)*tanhf(cn); }
        { float gi=a0[2]+xi.z, gf=a1[2]+xf.z, gg=a2[2]+xg.z, go=a3[2]+xo.z;
          float cn = sigmoidf_(gf)*c2 + sigmoidf_(gi)*tanhf(gg); c2 = cn; hv2 = sigmoidf_(go)*tanhf(cn); }
        { float gi=a0[3]+xi.w, gf=a1[3]+xf.w, gg=a2[3]+xg.w, go=a3[3]+xo.w;
          float cn = sigmoidf_(gf)*c3 + sigmoidf_(gi)*tanhf(gg); c3 = cn; hv3 = sigmoidf_(go)*tanhf(cn); }

        short4 hp;
        hp.x = (short)f2bf(hv0); hp.y = (short)f2bf(hv1);
        hp.z = (short)f2bf(hv2); hp.w = (short)f2bf(hv3);
        *(short4*)((char*)hbuf[nxt] + ((l15*512 + ubase*2) ^ xr)) = hp;
        int bg = bh*16 + l15;
        *(float4*)(&hcat[((size_t)bg*31 + t)*512 + (size_t)d*256 + ubase]) =
            make_float4(hv0, hv1, hv2, hv3);

        __syncthreads();
    }
#undef STAGE
#undef HRD
#undef MF
}

extern "C" void kernel_launch(void* const* d_in, const int* in_sizes, int n_in,
                              void* d_out, int out_size, void* d_ws, size_t ws_size,
                              hipStream_t stream)
{
    const float* x    = (const float*)d_in[0];
    const float* fW   = (const float*)d_in[1];
    const float* fB   = (const float*)d_in[2];
    const float* cbw1 = (const float*)d_in[3];
    const float* cbg  = (const float*)d_in[4];
    const float* cbb  = (const float*)d_in[5];
    const float* cbw2 = (const float*)d_in[6];
    const float* r1pg = (const float*)d_in[7];
    const float* r1pb = (const float*)d_in[8];
    const float* r1wA = (const float*)d_in[9];
    const float* r1g  = (const float*)d_in[10];
    const float* r1b  = (const float*)d_in[11];
    const float* r1wB = (const float*)d_in[12];
    const float* r1s  = (const float*)d_in[13];
    const float* r2pg = (const float*)d_in[14];
    const float* r2pb = (const float*)d_in[15];
    const float* r2wA = (const float*)d_in[16];
    const float* r2g  = (const float*)d_in[17];
    const float* r2b  = (const float*)d_in[18];
    const float* r2wB = (const float*)d_in[19];
    const float* r2s  = (const float*)d_in[20];
    const float* r3pg = (const float*)d_in[21];
    const float* r3pb = (const float*)d_in[22];
    const float* r3wA = (const float*)d_in[23];
    const float* r3g  = (const float*)d_in[24];
    const float* r3b  = (const float*)d_in[25];
    const float* r3wB = (const float*)d_in[26];
    const float* r3s  = (const float*)d_in[27];
    const float* pbg  = (const float*)d_in[28];
    const float* pbb  = (const float*)d_in[29];
    const float* wih_f = (const float*)d_in[30];
    const float* whh_f = (const float*)d_in[31];
    const float* bih_f = (const float*)d_in[32];
    const float* bhh_f = (const float*)d_in[33];
    const float* wih_b = (const float*)d_in[34];
    const float* whh_b = (const float*)d_in[35];
    const float* bih_b = (const float*)d_in[36];
    const float* bhh_b = (const float*)d_in[37];
    const float* clsw  = (const float*)d_in[38];
    const float* clsb  = (const float*)d_in[39];
    float* out = (float*)d_out;
    float* ws  = (float*)d_ws;

    // ---- workspace sizing ----
    const size_t FIXEDF = 5543872;
    // per-img shorts (all padded, all memset):
    //  A1 33*515*64=1,087,680  C1p 33*130*64=274,560  A2 33*130*128=549,120
    //  C2p 33*34*128=143,616   A3 33*34*192=215,424   XP3 34*10*192=65,280
    //  A4 34*10*256=87,040     total 2,422,720
    const size_t PCS = 2422720;
    const size_t PCF = (PCS + 1)/2;
    int NC = 0;
    const int cands[6] = {32,16,8,4,2,1};
    for (int i = 0; i < 6; ++i) {
        if ((FIXEDF + (size_t)cands[i]*PCF + 64)*sizeof(float) <= ws_size) { NC = cands[i]; break; }
    }
    if (!NC) return;

    float* p = ws;
    unsigned short* WTR = (unsigned short*)p; p += 962560;
    float* P   = p; p += 508896;
    float* XM  = p; p += 508896;
    unsigned short* XP4 = (unsigned short*)p; p += 253952;
    float* FE  = p; p += 507904;
    unsigned short* WF = (unsigned short*)p; p += 262144;
    float* XPT = p; p += 2031616;
    float* HC  = p; p += 507904;
    unsigned short* q = (unsigned short*)p;
    unsigned short* A1  = q; q += (size_t)NC*1087680;
    unsigned short* C1p = q; q += (size_t)NC*274560;
    unsigned short* A2  = q; q += (size_t)NC*549120;
    unsigned short* C2p = q; q += (size_t)NC*143616;
    unsigned short* A3  = q; q += (size_t)NC*215424;
    unsigned short* XP3 = q; q += (size_t)NC*65280;
    unsigned short* A4  = q; q += (size_t)NC*87040;

    unsigned short* w2T  = WTR + 0;
    unsigned short* r1AT = WTR + 36864;
    unsigned short* r1BT = WTR + 110592;
    unsigned short* r1ST = WTR + 258048;
    unsigned short* r2AT = WTR + 266240;
    unsigned short* r2BT = WTR + 487424;
    unsigned short* r2ST = WTR + 819200;
    unsigned short* r3AT = WTR + 843776;
    unsigned short* r3BT = WTR + 1286144;
    unsigned short* r3ST = WTR + 1875968;

    auto cdiv = [](int a, int b){ return (a + b - 1) / b; };

    // ---- weight transforms ----
    wtrans9_kernel<<<cdiv(9*64*64,256),   256, 0, stream>>>(cbw2, w2T, 64, 64);
    wtrans9_kernel<<<cdiv(9*128*64,256),  256, 0, stream>>>(r1wA, r1AT, 128, 64);
    wtrans9_kernel<<<cdiv(9*128*128,256), 256, 0, stream>>>(r1wB, r1BT, 128, 128);
    wtrans1_kernel<<<cdiv(128*64,256),    256, 0, stream>>>(r1s, r1ST, 128*64);
    wtrans9_kernel<<<cdiv(9*192*128,256), 256, 0, stream>>>(r2wA, r2AT, 192, 128);
    wtrans9_kernel<<<cdiv(9*192*192,256), 256, 0, stream>>>(r2wB, r2BT, 192, 192);
    wtrans1_kernel<<<cdiv(192*128,256),   256, 0, stream>>>(r2s, r2ST, 192*128);
    wtrans9_kernel<<<cdiv(9*256*192,256), 256, 0, stream>>>(r3wA, r3AT, 256, 192);
    wtrans9_kernel<<<cdiv(9*256*256,256), 256, 0, stream>>>(r3wB, r3BT, 256, 256);
    wtrans1_kernel<<<cdiv(256*192,256),   256, 0, stream>>>(r3s, r3ST, 256*192);
    whh_frag_kernel<<<1024, 256, 0, stream>>>(whh_f, WF);
    whh_frag_kernel<<<1024, 256, 0, stream>>>(whh_b, WF + 262144);

    // ---- frontend mask ----
    mask_partial_kernel<<<dim3(63, 32), 256, 0, stream>>>(fW, fB, P);
    mask_finalize_apply<<<63, 256, 0, stream>>>(P, x, XM);

    // ---- zero padded staging region (all halos stay zero) ----
    hipMemsetAsync(A1, 0, (size_t)NC*PCS*sizeof(unsigned short), stream);

    // ---- conv stack, chunked over batch ----
    for (int c0 = 0; c0 < 32; c0 += NC) {
        const float* xmc = XM + (size_t)c0*15903;
        conv1_kernel<<<dim3(63, 1, NC), 256, 0, stream>>>(xmc, cbw1, cbg, cbb, A1);
        // conv2 + bn+lrelu+pool4: 64ch, 513->128 -> C1p [33][130][64]
        conv_lds_kernel<64,8,0,1><<<dim3(4*31, 1, NC), 256, 0, stream>>>(
            A1, w2T, nullptr, nullptr, C1p, 515, 4, 0, 33, 1, 130, 1, 64, r1pg, r1pb);
        // r1A: 64->128 -> A2 [33][130][128]
        conv_lds_kernel<64,8,0,0><<<dim3(31, 2, NC), 256, 0, stream>>>(
            C1p, r1AT, nullptr, nullptr, A2, 130, 1, 0, 33, 1, 130, 1, 128, r1g, r1b);
        // r1B + shortcut + pool4: 128ch, 128->32 -> C2p [33][34][128]
        conv_lds_kernel<128,8,64,1><<<dim3(31, 2, NC), 256, 0, stream>>>(
            A2, r1BT, C1p, r1ST, C2p, 130, 1, 130, 33, 1, 34, 1, 128, r2pg, r2pb);
        // r2A: 128->192 -> A3 [33][34][192]
        conv_lds_kernel<128,2,0,0><<<dim3(31, 3, NC), 256, 0, stream>>>(
            C2p, r2AT, nullptr, nullptr, A3, 34, 1, 0, 33, 1, 34, 1, 192, r2g, r2b);
        // r2B + shortcut + pool4: 192ch, 32->8 -> XP3 [34][10][192] padded
        conv_lds_kernel<192,2,128,1><<<dim3(31, 3, NC), 256, 0, stream>>>(
            A3, r2BT, C2p, r2ST, XP3, 34, 1, 34, 34, 1, 10, 1, 192, r3pg, r3pb);
        // r3A: 192->256 -> A4 [34][10][256] padded
        conv_w8_kernel<192,0,0><<<dim3(16, 2, NC), 256, 0, stream>>>(
            XP3, r3AT, nullptr, nullptr, A4, 256, r3g, r3b);
        // r3B + shortcut + bn+lrelu+pool(8->2) -> XP4 slice directly
        conv_w8_kernel<256,192,1><<<dim3(16, 2, NC), 256, 0, stream>>>(
            A4, r3BT, XP3, r3ST, XP4 + (size_t)c0*15872, 256, pbg, pbb);
    }

    // feats (32,31,512) fp32
    feats_kernel<<<1984, 256, 0, stream>>>(XP4, FE);

    // LSTM input projections -> xpT [d][t][b][j]
    gemm_bias_kernel<1><<<dim3(31, 16), 256, 0, stream>>>(FE, wih_f, bih_f, bhh_f, XPT,           992, 1024, 512);
    gemm_bias_kernel<1><<<dim3(31, 16), 256, 0, stream>>>(FE, wih_b, bih_b, bhh_b, XPT + 1015808, 992, 1024, 512);

    // fused bidirectional scan (4 blocks: dir x batch-half)
    lstm_scan_mfma<<<4, 1024, 0, stream>>>(XPT, WF, HC);

    // classifier -> d_out (32,31,722)
    gemm_bias_kernel<0><<<dim3(31, 12), 256, 0, stream>>>(HC, clsw, clsb, nullptr, out, 992, 722, 512);
}

// Round 13
// 1368.826 us; speedup vs baseline: 1.1041x; 1.1041x over previous
//
#include <hip/hip_runtime.h>
#include <hip/hip_bf16.h>
#include <math.h>

#define RSQ 0.99999500003749969f   // 1/sqrt(1+1e-5)
#define SLOPE 0.01f

typedef __attribute__((ext_vector_type(8))) short short8;
typedef __attribute__((ext_vector_type(4))) float f32x4;

__device__ __forceinline__ float sigmoidf_(float x){ return 1.0f/(1.0f+expf(-x)); }

__device__ __forceinline__ unsigned short f2bf(float f){
    unsigned u = __float_as_uint(f);
    u += 0x7fff + ((u >> 16) & 1);      // RNE
    return (unsigned short)(u >> 16);
}
__device__ __forceinline__ float bf2f(unsigned short s){
    return __uint_as_float(((unsigned)s) << 16);
}

// async global->LDS, 16B per lane
__device__ __forceinline__ void stage16(const unsigned short* g, unsigned short* l) {
    __builtin_amdgcn_global_load_lds(
        (const __attribute__((address_space(1))) unsigned int*)g,
        (__attribute__((address_space(3))) unsigned int*)l, 16, 0, 0);
}

// ---------------- mask: prod_k cos(fW*rng + fB) ----------------
__global__ void mask_partial_kernel(const float* __restrict__ fW, const float* __restrict__ fB,
                                    float* __restrict__ partial)
{
    int p = blockIdx.x*256 + threadIdx.x;   // 0..15902
    if (p >= 15903) return;
    int w = p % 513;
    float r = (float)(w + 1);
    int k0 = blockIdx.y * 32;
    float prod = 1.0f;
    for (int k = k0; k < k0 + 32; ++k) {
        float a = fW[(size_t)k*15903 + p] * r + fB[(size_t)k*15903 + p];
        prod *= cosf(a);
    }
    partial[blockIdx.y*15903 + p] = prod;
}

__global__ void mask_finalize_apply(const float* __restrict__ partial, const float* __restrict__ x,
                                    float* __restrict__ xm)
{
    int p = blockIdx.x*256 + threadIdx.x;
    if (p >= 15903) return;
    float m = 1.0f;
    #pragma unroll
    for (int c = 0; c < 32; ++c) m *= partial[c*15903 + p];
    for (int n = 0; n < 32; ++n)
        xm[(size_t)n*15903 + p] = x[(size_t)n*15903 + p] * m;
}

// ---------------- weight transforms ----------------
__global__ void wtrans9_kernel(const float* __restrict__ w, unsigned short* __restrict__ o,
                               int Cout, int Cin)
{
    int idx = blockIdx.x*256 + threadIdx.x;
    int cc = Cout*Cin;
    if (idx >= 9*cc) return;
    int tap = idx / cc;
    int r = idx - tap*cc;
    int co = r / Cin, ci = r - co*Cin;
    int kh = tap/3, kw = tap - kh*3;
    o[idx] = f2bf(w[((size_t)(co*Cin + ci)*3 + kh)*3 + kw]);
}
__global__ void wtrans1_kernel(const float* __restrict__ w, unsigned short* __restrict__ o, int total)
{
    int idx = blockIdx.x*256 + threadIdx.x;
    if (idx < total) o[idx] = f2bf(w[idx]);
}

// whh (1024,256) fp32 -> MFMA-fragment-contiguous bf16
__global__ void whh_frag_kernel(const float* __restrict__ whh, unsigned short* __restrict__ out)
{
    int tid = blockIdx.x*256 + threadIdx.x;  // 262144 exact
    int e    = tid & 7;
    int lane = (tid >> 3) & 63;
    int kc   = (tid >> 9) & 7;
    int u0   = (tid >> 12) & 15;
    int g    = tid >> 16;
    int j = (g << 8) + (u0 << 4) + (lane & 15);
    int k = (kc << 5) + ((lane >> 4) << 3) + e;
    out[tid] = f2bf(whh[(size_t)j*256 + k]);
}

// ---------------- conv1: Cin=1 direct, fp32 in -> bf16 NHWC (rows 1..31 of [33][515][64]) ----------------
__launch_bounds__(256)
__global__ void conv1_kernel(const float* __restrict__ xm, const float* __restrict__ w1,
                             const float* __restrict__ g, const float* __restrict__ b,
                             unsigned short* __restrict__ O)
{
    __shared__ float wl[576];
    __shared__ float sg[64], sb[64];
    int tid = threadIdx.x;
    if (tid < 64) { sg[tid] = g[tid]*RSQ; sb[tid] = b[tid]; }
    for (int i = tid; i < 576; i += 256) wl[i] = w1[i];
    __syncthreads();
    int px = blockIdx.x*256 + tid;
    int n = blockIdx.z;
    if (px >= 15903) return;
    int h = px / 513, w = px - h*513;
    const float* xp = xm + (size_t)n*15903;
    float v[9];
    #pragma unroll
    for (int dh = 0; dh < 3; ++dh)
      #pragma unroll
      for (int dw = 0; dw < 3; ++dw) {
        int hh = h+dh-1, ww = w+dw-1;
        bool ok = ((unsigned)hh < 31u) && ((unsigned)ww < 513u);
        v[dh*3+dw] = ok ? xp[hh*513 + ww] : 0.f;
      }
    unsigned short* op = O + (((size_t)(n*33 + h + 1))*515 + (w + 1))*64;
    #pragma unroll
    for (int c8 = 0; c8 < 8; ++c8) {
        unsigned tmp[8];
        #pragma unroll
        for (int j = 0; j < 8; ++j) {
            int co = c8*8 + j;
            const float* wr = &wl[co*9];
            float a = 0.f;
            #pragma unroll
            for (int t2 = 0; t2 < 9; ++t2) a += wr[t2]*v[t2];
            a = a*sg[co] + sb[co];
            a = (a >= 0.f) ? a : SLOPE*a;
            tmp[j] = f2bf(a);
        }
        uint4 pk;
        pk.x = tmp[0] | (tmp[1]<<16);
        pk.y = tmp[2] | (tmp[3]<<16);
        pk.z = tmp[4] | (tmp[5]<<16);
        pk.w = tmp[6] | (tmp[7]<<16);
        *(uint4*)(op + c8*8) = pk;
    }
}

// ---------------- LDS-staged implicit-GEMM 3x3 conv (+1x1 shortcut) via MFMA ----------------
// (round-11 form: 4 waves x 16 co, per-dh weight burst, full TPX per wave)
template<int CIN, int TPX, int CS, int POOL>
__launch_bounds__(256, 2)
__global__ void conv_lds_kernel(const unsigned short* __restrict__ X,
                                const unsigned short* __restrict__ W9,
                                const unsigned short* __restrict__ Xs,
                                const unsigned short* __restrict__ Ws,
                                unsigned short* __restrict__ O,
                                int Wp, int WT, int WpS,
                                int HO, int HOFF, int WpO, int OOFF, int Cout,
                                const float* __restrict__ g, const float* __restrict__ b)
{
    constexpr int KQ  = CIN/8;
    constexpr int PXT = TPX*16 + 2;
    constexpr int UX  = 3*PXT*KQ;
    constexpr int KQS = (CS > 0) ? CS/8 : 8;
    constexpr int US  = (CS > 0) ? TPX*16*KQS : 0;
    constexpr int UT  = UX + US;
    constexpr int NU  = (UT + 255)/256;
    constexpr int NKC = CIN/32;
    __shared__ uint4 lds4[UT + 8];

    const int tid = threadIdx.x;
    const int lane = tid & 63;
    const int wave = tid >> 6;
    const int cob  = blockIdx.y*64 + wave*16;
    const int n  = blockIdx.z;
    const int wt = blockIdx.x % WT;
    const int h  = blockIdx.x / WT;
    const int w0 = wt*(TPX*16);
    const int l15 = lane & 15;
    const int gq  = lane >> 4;

    uint4 tmp[NU];
    #pragma unroll
    for (int i = 0; i < NU; ++i) {
        int u = tid + i*256;
        if (u < UX) {
            int r   = u / (PXT*KQ);
            int rem = u - r*(PXT*KQ);
            int px  = rem / KQ;
            int kq  = rem - px*KQ;
            tmp[i] = *(const uint4*)(X + (((size_t)(n*33 + h + r))*Wp + w0 + px)*CIN + kq*8);
        } else if (CS > 0 && u < UT) {
            int us = u - UX;
            int px = us / KQS;
            int kq = us - px*KQS;
            tmp[i] = *(const uint4*)(Xs + (((size_t)(n*33 + h + 1))*WpS + w0 + 1 + px)*CS + kq*8);
        }
    }
    #pragma unroll
    for (int i = 0; i < NU; ++i) {
        int u = tid + i*256;
        if (u < UT) {
            int px;
            if (u < UX) { int rem = u % (PXT*KQ); px = rem / KQ; }
            else        { px = (u - UX) / KQS; }
            *(uint4*)((char*)lds4 + ((u*16) ^ ((px & 7) << 4))) = tmp[i];
        }
    }
    __syncthreads();

    f32x4 acc[TPX] = {};
    #pragma unroll
    for (int dh = 0; dh < 3; ++dh) {
        short8 aw[3*NKC];
        #pragma unroll
        for (int dw = 0; dw < 3; ++dw)
            #pragma unroll
            for (int kc = 0; kc < NKC; ++kc)
                aw[dw*NKC + kc] = *(const short8*)(W9 +
                    ((size_t)((dh*3 + dw)*Cout + cob + l15))*CIN + kc*32 + gq*8);
        #pragma unroll
        for (int dw = 0; dw < 3; ++dw) {
            #pragma unroll
            for (int kc = 0; kc < NKC; ++kc) {
                short8 a = aw[dw*NKC + kc];
                #pragma unroll
                for (int t = 0; t < TPX; ++t) {
                    int px = dw + t*16 + l15;
                    int u  = (dh*PXT + px)*KQ + kc*4 + gq;
                    short8 bv = *(const short8*)((const char*)lds4 + ((u*16) ^ ((px & 7) << 4)));
                    acc[t] = __builtin_amdgcn_mfma_f32_16x16x32_bf16(a, bv, acc[t], 0, 0, 0);
                }
            }
        }
    }

    if (CS > 0) {
        #pragma unroll
        for (int kc = 0; kc < KQS/4; ++kc) {
            short8 a = *(const short8*)(Ws + (size_t)(cob + l15)*CS + kc*32 + gq*8);
            #pragma unroll
            for (int t = 0; t < TPX; ++t) {
                int px = t*16 + l15;
                int u  = UX + px*KQS + kc*4 + gq;
                short8 bv = *(const short8*)((const char*)lds4 + ((u*16) ^ ((px & 7) << 4)));
                acc[t] = __builtin_amdgcn_mfma_f32_16x16x32_bf16(a, bv, acc[t], 0, 0, 0);
            }
        }
    }

    int cb = cob + gq*4;
    float s0 = g[cb+0]*RSQ, s1 = g[cb+1]*RSQ, s2 = g[cb+2]*RSQ, s3 = g[cb+3]*RSQ;
    float o0 = b[cb+0], o1 = b[cb+1], o2 = b[cb+2], o3 = b[cb+3];
    #pragma unroll
    for (int t = 0; t < TPX; ++t) {
        float v0 = acc[t][0]*s0 + o0; v0 = (v0 >= 0.f) ? v0 : SLOPE*v0;
        float v1 = acc[t][1]*s1 + o1; v1 = (v1 >= 0.f) ? v1 : SLOPE*v1;
        float v2 = acc[t][2]*s2 + o2; v2 = (v2 >= 0.f) ? v2 : SLOPE*v2;
        float v3 = acc[t][3]*s3 + o3; v3 = (v3 >= 0.f) ? v3 : SLOPE*v3;
        if (POOL) {
            v0 = fmaxf(v0, __shfl_xor(v0, 1)); v0 = fmaxf(v0, __shfl_xor(v0, 2));
            v1 = fmaxf(v1, __shfl_xor(v1, 1)); v1 = fmaxf(v1, __shfl_xor(v1, 2));
            v2 = fmaxf(v2, __shfl_xor(v2, 1)); v2 = fmaxf(v2, __shfl_xor(v2, 2));
            v3 = fmaxf(v3, __shfl_xor(v3, 1)); v3 = fmaxf(v3, __shfl_xor(v3, 2));
            if ((l15 & 3) == 0) {
                int pw = (w0 + t*16 + l15) >> 2;
                uint2 pk;
                pk.x = (unsigned)f2bf(v0) | ((unsigned)f2bf(v1) << 16);
                pk.y = (unsigned)f2bf(v2) | ((unsigned)f2bf(v3) << 16);
                *(uint2*)(O + (((size_t)(n*HO + h + HOFF))*WpO + pw + OOFF)*Cout + cb) = pk;
            }
        } else {
            int w = w0 + t*16 + l15;
            uint2 pk;
            pk.x = (unsigned)f2bf(v0) | ((unsigned)f2bf(v1) << 16);
            pk.y = (unsigned)f2bf(v2) | ((unsigned)f2bf(v3) << 16);
            *(uint2*)(O + (((size_t)(n*HO + h + HOFF))*WpO + w + OOFF)*Cout + cb) = pk;
        }
    }
}

// ---------------- W=8 LDS-staged conv for r3 layers ----------------
template<int CIN, int CS, int POOL>
__launch_bounds__(256, 2)
__global__ void conv_w8_kernel(const unsigned short* __restrict__ X,
                               const unsigned short* __restrict__ W9,
                               const unsigned short* __restrict__ Xs,
                               const unsigned short* __restrict__ Ws,
                               unsigned short* __restrict__ O, int Cout,
                               const float* __restrict__ g, const float* __restrict__ b)
{
    constexpr int KQ  = CIN/8;
    constexpr int UX  = 4*10*KQ;
    constexpr int KQS = (CS > 0) ? CS/8 : 8;
    constexpr int US  = (CS > 0) ? 2*8*KQS : 0;
    constexpr int UT  = UX + US;
    constexpr int NU  = (UT + 255)/256;
    constexpr int NKC = CIN/32;
    __shared__ uint4 lds4[UT + 8];

    const int tid = threadIdx.x;
    const int lane = tid & 63;
    const int wave = tid >> 6;
    const int hp = blockIdx.x;          // 0..15
    const int n  = blockIdx.z;
    const int h0 = hp*2;
    const int l15 = lane & 15;
    const int gq  = lane >> 4;
    const int r = l15 >> 3;
    const int w = l15 & 7;
    const int cwb = blockIdx.y*128 + wave*32;

    uint4 tmp[NU];
    #pragma unroll
    for (int i = 0; i < NU; ++i) {
        int u = tid + i*256;
        if (u < UX) {
            int row = u / (10*KQ);
            int rem = u - row*(10*KQ);
            int px  = rem / KQ;
            int kq  = rem - px*KQ;
            tmp[i] = *(const uint4*)(X + (((size_t)(n*34 + h0 + row))*10 + px)*CIN + kq*8);
        } else if (CS > 0 && u < UT) {
            int us = u - UX;
            int rs = us / (8*KQS);
            int rem = us - rs*(8*KQS);
            int px8 = rem / KQS;
            int kq  = rem - px8*KQS;
            tmp[i] = *(const uint4*)(Xs + (((size_t)(n*34 + h0 + 1 + rs))*10 + px8 + 1)*CS + kq*8);
        }
    }
    #pragma unroll
    for (int i = 0; i < NU; ++i) {
        int u = tid + i*256;
        if (u < UT) {
            int key;
            if (u < UX) { int rem = u % (10*KQ); key = rem / KQ; }
            else        { key = ((u - UX) % (8*KQS)) / KQS; }
            *(uint4*)((char*)lds4 + ((u*16) ^ ((key & 7) << 4))) = tmp[i];
        }
    }
    __syncthreads();

    f32x4 acc0 = {0,0,0,0}, acc1 = {0,0,0,0};
    #pragma unroll
    for (int dh = 0; dh < 3; ++dh) {
        #pragma unroll
        for (int dw = 0; dw < 3; ++dw) {
            short8 a0[NKC], a1[NKC];
            #pragma unroll
            for (int kc = 0; kc < NKC; ++kc) {
                a0[kc] = *(const short8*)(W9 + ((size_t)((dh*3+dw)*Cout + cwb + l15))*CIN + kc*32 + gq*8);
                a1[kc] = *(const short8*)(W9 + ((size_t)((dh*3+dw)*Cout + cwb + 16 + l15))*CIN + kc*32 + gq*8);
            }
            #pragma unroll
            for (int kc = 0; kc < NKC; ++kc) {
                int row_s = r + dh;
                int col = w + dw;
                int u = (row_s*10 + col)*KQ + kc*4 + gq;
                short8 bv = *(const short8*)((const char*)lds4 + ((u*16) ^ ((col & 7) << 4)));
                acc0 = __builtin_amdgcn_mfma_f32_16x16x32_bf16(a0[kc], bv, acc0, 0, 0, 0);
                acc1 = __builtin_amdgcn_mfma_f32_16x16x32_bf16(a1[kc], bv, acc1, 0, 0, 0);
            }
        }
    }

    if (CS > 0) {
        #pragma unroll
        for (int kc = 0; kc < KQS/4; ++kc) {
            short8 a0 = *(const short8*)(Ws + (size_t)(cwb + l15)*CS + kc*32 + gq*8);
            short8 a1 = *(const short8*)(Ws + (size_t)(cwb + 16 + l15)*CS + kc*32 + gq*8);
            int u = UX + (r*8 + w)*KQS + kc*4 + gq;
            short8 bv = *(const short8*)((const char*)lds4 + ((u*16) ^ ((w & 7) << 4)));
            acc0 = __builtin_amdgcn_mfma_f32_16x16x32_bf16(a0, bv, acc0, 0, 0, 0);
            acc1 = __builtin_amdgcn_mfma_f32_16x16x32_bf16(a1, bv, acc1, 0, 0, 0);
        }
    }

    const int hr = h0 + r;
    const bool valid = hr < 31;
#define EPIG8(ACC, G) do { \
    int cb = cwb + (G)*16 + gq*4; \
    float s0 = g[cb+0]*RSQ, s1 = g[cb+1]*RSQ, s2 = g[cb+2]*RSQ, s3 = g[cb+3]*RSQ; \
    float o0 = b[cb+0], o1 = b[cb+1], o2 = b[cb+2], o3 = b[cb+3]; \
    float v0 = ACC[0]*s0 + o0; v0 = (v0 >= 0.f) ? v0 : SLOPE*v0; \
    float v1 = ACC[1]*s1 + o1; v1 = (v1 >= 0.f) ? v1 : SLOPE*v1; \
    float v2 = ACC[2]*s2 + o2; v2 = (v2 >= 0.f) ? v2 : SLOPE*v2; \
    float v3 = ACC[3]*s3 + o3; v3 = (v3 >= 0.f) ? v3 : SLOPE*v3; \
    if (POOL) { \
        v0 = fmaxf(v0, __shfl_xor(v0, 1)); v0 = fmaxf(v0, __shfl_xor(v0, 2)); \
        v1 = fmaxf(v1, __shfl_xor(v1, 1)); v1 = fmaxf(v1, __shfl_xor(v1, 2)); \
        v2 = fmaxf(v2, __shfl_xor(v2, 1)); v2 = fmaxf(v2, __shfl_xor(v2, 2)); \
        v3 = fmaxf(v3, __shfl_xor(v3, 1)); v3 = fmaxf(v3, __shfl_xor(v3, 2)); \
        if (((l15 & 3) == 0) && valid) { \
            uint2 pk; \
            pk.x = (unsigned)f2bf(v0) | ((unsigned)f2bf(v1) << 16); \
            pk.y = (unsigned)f2bf(v2) | ((unsigned)f2bf(v3) << 16); \
            *(uint2*)(O + (((size_t)(n*31 + hr))*2 + (w >> 2))*Cout + cb) = pk; \
        } \
    } else if (valid) { \
        uint2 pk; \
        pk.x = (unsigned)f2bf(v0) | ((unsigned)f2bf(v1) << 16); \
        pk.y = (unsigned)f2bf(v2) | ((unsigned)f2bf(v3) << 16); \
        *(uint2*)(O + (((size_t)(n*34 + hr + 1))*10 + w + 1)*Cout + cb) = pk; \
    } \
} while(0)
    EPIG8(acc0, 0);
    EPIG8(acc1, 1);
#undef EPIG8
}

// ---------------- feats: [n][31][2][256] bf16 NHWC -> [n][31][512] fp32 ----------------
__global__ void feats_kernel(const unsigned short* __restrict__ p4, float* __restrict__ fe)
{
    int idx = blockIdx.x*256 + threadIdx.x;   // 507904
    int cw = idx & 511;
    int nh = idx >> 9;
    int c = cw >> 1, w = cw & 1;
    fe[idx] = bf2f(p4[((size_t)nh*2 + w)*256 + c]);
}

// ---------------- tiled SGEMM: C[M,N] = A[M,K] @ B[N,K]^T + bias(+bias2) ----------------
#define GM 32
#define GN 64
#define GK 32
template<int XPOSE>
__launch_bounds__(256)
__global__ void gemm_bias_kernel(const float* __restrict__ A, const float* __restrict__ B,
                                 const float* __restrict__ bias, const float* __restrict__ bias2,
                                 float* __restrict__ C, int M, int N, int K)
{
    __shared__ float As[GM][GK+1];
    __shared__ float Bs[GN][GK+1];
    int m0 = blockIdx.x*GM, n0 = blockIdx.y*GN;
    int tid = threadIdx.x;
    int mi = tid >> 4;
    int ni = (tid & 15) * 4;
    float acc[2][4] = {};

    for (int k0 = 0; k0 < K; k0 += GK) {
        for (int i = tid; i < GM*GK; i += 256) {
            int r = i >> 5, c = i & 31;
            int m = m0 + r;
            As[r][c] = (m < M) ? A[(size_t)m*K + k0 + c] : 0.f;
        }
        for (int i = tid; i < GN*GK; i += 256) {
            int r = i >> 5, c = i & 31;
            int n = n0 + r;
            Bs[r][c] = (n < N) ? B[(size_t)n*K + k0 + c] : 0.f;
        }
        __syncthreads();
        #pragma unroll
        for (int kk = 0; kk < GK; ++kk) {
            float a0 = As[mi][kk], a1 = As[mi+16][kk];
            float b0 = Bs[ni][kk], b1 = Bs[ni+1][kk], b2 = Bs[ni+2][kk], b3 = Bs[ni+3][kk];
            acc[0][0] += a0*b0; acc[0][1] += a0*b1; acc[0][2] += a0*b2; acc[0][3] += a0*b3;
            acc[1][0] += a1*b0; acc[1][1] += a1*b1; acc[1][2] += a1*b2; acc[1][3] += a1*b3;
        }
        __syncthreads();
    }
    #pragma unroll
    for (int r = 0; r < 2; ++r) {
        int m = m0 + mi + r*16;
        if (m >= M) continue;
        #pragma unroll
        for (int q = 0; q < 4; ++q) {
            int n = n0 + ni + q;
            if (n >= N) continue;
            float v = acc[r][q];
            if (bias)  v += bias[n];
            if (bias2) v += bias2[n];
            if (XPOSE) C[((size_t)(m % 31)*32 + (m / 31))*N + n] = v;
            else       C[(size_t)m*N + n] = v;
        }
    }
}

// ---------------- LSTM scan via MFMA + global_load_lds weight pipeline ----------------
__launch_bounds__(1024)
__global__ void lstm_scan_mfma(const float* __restrict__ xpT,
                               const unsigned short* __restrict__ wf,
                               float* __restrict__ hcat)
{
    const int d  = blockIdx.x >> 1;
    const int bh = blockIdx.x & 1;
    const int tid = threadIdx.x;
    const int u0 = tid >> 6;
    const int lane = tid & 63;
    const int l15 = lane & 15;
    const int q = lane >> 4;

    __shared__ unsigned short hbuf[2][4096];          // 16 KB
    __shared__ unsigned short wst[16][2][2048];       // 128 KB

    ((int4*)hbuf)[tid & 1023] = make_int4(0,0,0,0);

    const unsigned short* wfd = wf + (size_t)d*262144;
    const float* xpd = xpT + (size_t)d*992*1024 + (size_t)bh*16*1024;
    const unsigned short* wsrc = wfd + (size_t)u0*4096 + (size_t)lane*8;
    unsigned short* wl = &wst[u0][0][0];

#define STAGE(KC, PB) do { \
    unsigned short* dst_ = wl + (PB)*2048; \
    stage16(wsrc + 0*65536 + (KC)*512, dst_ + 0*512); \
    stage16(wsrc + 1*65536 + (KC)*512, dst_ + 1*512); \
    stage16(wsrc + 2*65536 + (KC)*512, dst_ + 2*512); \
    stage16(wsrc + 3*65536 + (KC)*512, dst_ + 3*512); \
} while(0)

    STAGE(0, 0);
    __syncthreads();

    float c0=0.f, c1=0.f, c2=0.f, c3=0.f;
    const int ubase = u0*16 + q*4;
    const int rb = l15*512 + q*16;
    const int xr = (l15&7)<<4;

#define HRD(kc)   (*(const short8*)(hb + ((rb + (kc)*64) ^ xr)))
#define MF(w_,h_,a_) a_ = __builtin_amdgcn_mfma_f32_16x16x32_bf16(w_, h_, a_, 0, 0, 0)

    for (int s = 0; s < 31; ++s) {
        const int t = d ? (30 - s) : s;
        const int cur = s & 1, nxt = cur ^ 1;
        const float* xb = xpd + (size_t)t*32768 + (size_t)l15*1024;
        float4 xi = *(const float4*)(xb + ubase);
        float4 xf = *(const float4*)(xb + 256 + ubase);
        float4 xg = *(const float4*)(xb + 512 + ubase);
        float4 xo = *(const float4*)(xb + 768 + ubase);

        const char* hb = (const char*)hbuf[cur];
        f32x4 a0={0,0,0,0}, a1={0,0,0,0}, a2={0,0,0,0}, a3={0,0,0,0};

        #pragma unroll
        for (int kc = 0; kc < 8; ++kc) {
            if (kc < 7) STAGE(kc+1, (kc+1)&1);
            else        STAGE(0, 0);
            if (kc == 0) asm volatile("s_waitcnt vmcnt(8)" ::: "memory");
            else         asm volatile("s_waitcnt vmcnt(4)" ::: "memory");
            const unsigned short* wb = wl + (kc&1)*2048;
            short8 w0 = *(const short8*)(wb + 0*512 + lane*8);
            short8 w1 = *(const short8*)(wb + 1*512 + lane*8);
            short8 w2 = *(const short8*)(wb + 2*512 + lane*8);
            short8 w3 = *(const short8*)(wb + 3*512 + lane*8);
            short8 h = HRD(kc);
            MF(w0,h,a0); MF(w1,h,a1); MF(w2,h,a2); MF(w3,h,a3);
        }

        float hv0, hv1, hv2, hv3;
        { float gi=a0[0]+xi.x, gf=a1[0]+xf.x, gg=a2[0]+xg.x, go=a3[0]+xo.x;
          float cn = sigmoidf_(gf)*c0 + sigmoidf_(gi)*tanhf(gg); c0 = cn; hv0 = sigmoidf_(go)*tanhf(cn); }
        { float gi=a0[1]+xi.y, gf=a1[1]+xf.y, gg=a2[1]+xg.y, go=a3[1]+xo.y;
          float cn = sigmoidf_(gf)*c1 + sigmoidf_(gi)*tanhf(gg); c1 = cn; hv1 = sigmoidf_(go)*tanhf(cn); }
        { float gi=a0[2]+xi.z, gf=a1[2]+xf.z, gg=a2[2]+xg.z, go=a3[2]+xo.z;
          float cn = sigmoidf_(gf)*c2 + sigmoidf_(gi)*tanhf(gg); c2 = cn; hv2 = sigmoidf_(go)*tanhf(cn); }
        { float gi=a0[3]+xi.w, gf=a1[3]+xf.w, gg=a2[3]+xg.w, go=a3[3]+xo.w;
          float cn = sigmoidf_(gf)*c3 + sigmoidf_(gi)*tanhf(gg); c3 = cn; hv3 = sigmoidf_(go)*tanhf(cn); }

        short4 hp;
        hp.x = (short)f2bf(hv0); hp.y = (short)f2bf(hv1);
        hp.z = (short)f2bf(hv2); hp.w = (short)f2bf(hv3);
        *(short4*)((char*)hbuf[nxt] + ((l15*512 + ubase*2) ^ xr)) = hp;
        int bg = bh*16 + l15;
        *(float4*)(&hcat[((size_t)bg*31 + t)*512 + (size_t)d*256 + ubase]) =
            make_float4(hv0, hv1, hv2, hv3);

        __syncthreads();
    }
#undef STAGE
#undef HRD
#undef MF
}

extern "C" void kernel_launch(void* const* d_in, const int* in_sizes, int n_in,
                              void* d_out, int out_size, void* d_ws, size_t ws_size,
                              hipStream_t stream)
{
    const float* x    = (const float*)d_in[0];
    const float* fW   = (const float*)d_in[1];
    const float* fB   = (const float*)d_in[2];
    const float* cbw1 = (const float*)d_in[3];
    const float* cbg  = (const float*)d_in[4];
    const float* cbb  = (const float*)d_in[5];
    const float* cbw2 = (const float*)d_in[6];
    const float* r1pg = (const float*)d_in[7];
    const float* r1pb = (const float*)d_in[8];
    const float* r1wA = (const float*)d_in[9];
    const float* r1g  = (const float*)d_in[10];
    const float* r1b  = (const float*)d_in[11];
    const float* r1wB = (const float*)d_in[12];
    const float* r1s  = (const float*)d_in[13];
    const float* r2pg = (const float*)d_in[14];
    const float* r2pb = (const float*)d_in[15];
    const float* r2wA = (const float*)d_in[16];
    const float* r2g  = (const float*)d_in[17];
    const float* r2b  = (const float*)d_in[18];
    const float* r2wB = (const float*)d_in[19];
    const float* r2s  = (const float*)d_in[20];
    const float* r3pg = (const float*)d_in[21];
    const float* r3pb = (const float*)d_in[22];
    const float* r3wA = (const float*)d_in[23];
    const float* r3g  = (const float*)d_in[24];
    const float* r3b  = (const float*)d_in[25];
    const float* r3wB = (const float*)d_in[26];
    const float* r3s  = (const float*)d_in[27];
    const float* pbg  = (const float*)d_in[28];
    const float* pbb  = (const float*)d_in[29];
    const float* wih_f = (const float*)d_in[30];
    const float* whh_f = (const float*)d_in[31];
    const float* bih_f = (const float*)d_in[32];
    const float* bhh_f = (const float*)d_in[33];
    const float* wih_b = (const float*)d_in[34];
    const float* whh_b = (const float*)d_in[35];
    const float* bih_b = (const float*)d_in[36];
    const float* bhh_b = (const float*)d_in[37];
    const float* clsw  = (const float*)d_in[38];
    const float* clsb  = (const float*)d_in[39];
    float* out = (float*)d_out;
    float* ws  = (float*)d_ws;

    // ---- workspace sizing ----
    const size_t FIXEDF = 5543872;
    // per-img shorts (all padded, all memset):
    //  A1 1,087,680  C1p 274,560  A2 549,120  C2p 143,616  A3 215,424
    //  XP3 65,280  A4 87,040  total 2,422,720
    const size_t PCS = 2422720;
    const size_t PCF = (PCS + 1)/2;
    int NC = 0;
    const int cands[6] = {32,16,8,4,2,1};
    for (int i = 0; i < 6; ++i) {
        if ((FIXEDF + (size_t)cands[i]*PCF + 64)*sizeof(float) <= ws_size) { NC = cands[i]; break; }
    }
    if (!NC) return;

    float* p = ws;
    unsigned short* WTR = (unsigned short*)p; p += 962560;
    float* P   = p; p += 508896;
    float* XM  = p; p += 508896;
    unsigned short* XP4 = (unsigned short*)p; p += 253952;
    float* FE  = p; p += 507904;
    unsigned short* WF = (unsigned short*)p; p += 262144;
    float* XPT = p; p += 2031616;
    float* HC  = p; p += 507904;
    unsigned short* q = (unsigned short*)p;
    unsigned short* A1  = q; q += (size_t)NC*1087680;
    unsigned short* C1p = q; q += (size_t)NC*274560;
    unsigned short* A2  = q; q += (size_t)NC*549120;
    unsigned short* C2p = q; q += (size_t)NC*143616;
    unsigned short* A3  = q; q += (size_t)NC*215424;
    unsigned short* XP3 = q; q += (size_t)NC*65280;
    unsigned short* A4  = q; q += (size_t)NC*87040;

    unsigned short* w2T  = WTR + 0;
    unsigned short* r1AT = WTR + 36864;
    unsigned short* r1BT = WTR + 110592;
    unsigned short* r1ST = WTR + 258048;
    unsigned short* r2AT = WTR + 266240;
    unsigned short* r2BT = WTR + 487424;
    unsigned short* r2ST = WTR + 819200;
    unsigned short* r3AT = WTR + 843776;
    unsigned short* r3BT = WTR + 1286144;
    unsigned short* r3ST = WTR + 1875968;

    auto cdiv = [](int a, int b){ return (a + b - 1) / b; };

    // ---- weight transforms ----
    wtrans9_kernel<<<cdiv(9*64*64,256),   256, 0, stream>>>(cbw2, w2T, 64, 64);
    wtrans9_kernel<<<cdiv(9*128*64,256),  256, 0, stream>>>(r1wA, r1AT, 128, 64);
    wtrans9_kernel<<<cdiv(9*128*128,256), 256, 0, stream>>>(r1wB, r1BT, 128, 128);
    wtrans1_kernel<<<cdiv(128*64,256),    256, 0, stream>>>(r1s, r1ST, 128*64);
    wtrans9_kernel<<<cdiv(9*192*128,256), 256, 0, stream>>>(r2wA, r2AT, 192, 128);
    wtrans9_kernel<<<cdiv(9*192*192,256), 256, 0, stream>>>(r2wB, r2BT, 192, 192);
    wtrans1_kernel<<<cdiv(192*128,256),   256, 0, stream>>>(r2s, r2ST, 192*128);
    wtrans9_kernel<<<cdiv(9*256*192,256), 256, 0, stream>>>(r3wA, r3AT, 256, 192);
    wtrans9_kernel<<<cdiv(9*256*256,256), 256, 0, stream>>>(r3wB, r3BT, 256, 256);
    wtrans1_kernel<<<cdiv(256*192,256),   256, 0, stream>>>(r3s, r3ST, 256*192);
    whh_frag_kernel<<<1024, 256, 0, stream>>>(whh_f, WF);
    whh_frag_kernel<<<1024, 256, 0, stream>>>(whh_b, WF + 262144);

    // ---- frontend mask ----
    mask_partial_kernel<<<dim3(63, 32), 256, 0, stream>>>(fW, fB, P);
    mask_finalize_apply<<<63, 256, 0, stream>>>(P, x, XM);

    // ---- zero padded staging region (all halos stay zero) ----
    hipMemsetAsync(A1, 0, (size_t)NC*PCS*sizeof(unsigned short), stream);

    // ---- conv stack, chunked over batch ----
    for (int c0 = 0; c0 < 32; c0 += NC) {
        const float* xmc = XM + (size_t)c0*15903;
        conv1_kernel<<<dim3(63, 1, NC), 256, 0, stream>>>(xmc, cbw1, cbg, cbb, A1);
        // conv2 + bn+lrelu+pool4: 64ch, 513->128 -> C1p [33][130][64]
        conv_lds_kernel<64,8,0,1><<<dim3(4*31, 1, NC), 256, 0, stream>>>(
            A1, w2T, nullptr, nullptr, C1p, 515, 4, 0, 33, 1, 130, 1, 64, r1pg, r1pb);
        // r1A: 64->128 -> A2 [33][130][128]
        conv_lds_kernel<64,8,0,0><<<dim3(31, 2, NC), 256, 0, stream>>>(
            C1p, r1AT, nullptr, nullptr, A2, 130, 1, 0, 33, 1, 130, 1, 128, r1g, r1b);
        // r1B + shortcut + pool4: 128ch, 128->32 -> C2p [33][34][128]
        conv_lds_kernel<128,8,64,1><<<dim3(31, 2, NC), 256, 0, stream>>>(
            A2, r1BT, C1p, r1ST, C2p, 130, 1, 130, 33, 1, 34, 1, 128, r2pg, r2pb);
        // r2A: 128->192 -> A3 [33][34][192]
        conv_lds_kernel<128,2,0,0><<<dim3(31, 3, NC), 256, 0, stream>>>(
            C2p, r2AT, nullptr, nullptr, A3, 34, 1, 0, 33, 1, 34, 1, 192, r2g, r2b);
        // r2B + shortcut + pool4: 192ch, 32->8 -> XP3 [34][10][192] padded
        conv_lds_kernel<192,2,128,1><<<dim3(31, 3, NC), 256, 0, stream>>>(
            A3, r2BT, C2p, r2ST, XP3, 34, 1, 34, 34, 1, 10, 1, 192, r3pg, r3pb);
        // r3A: 192->256 -> A4 [34][10][256] padded
        conv_w8_kernel<192,0,0><<<dim3(16, 2, NC), 256, 0, stream>>>(
            XP3, r3AT, nullptr, nullptr, A4, 256, r3g, r3b);
        // r3B + shortcut + bn+lrelu+pool(8->2) -> XP4 slice directly
        conv_w8_kernel<256,192,1><<<dim3(16, 2, NC), 256, 0, stream>>>(
            A4, r3BT, XP3, r3ST, XP4 + (size_t)c0*15872, 256, pbg, pbb);
    }

    // feats (32,31,512) fp32
    feats_kernel<<<1984, 256, 0, stream>>>(XP4, FE);

    // LSTM input projections -> xpT [d][t][b][j]
    gemm_bias_kernel<1><<<dim3(31, 16), 256, 0, stream>>>(FE, wih_f, bih_f, bhh_f, XPT,           992, 1024, 512);
    gemm_bias_kernel<1><<<dim3(31, 16), 256, 0, stream>>>(FE, wih_b, bih_b, bhh_b, XPT + 1015808, 992, 1024, 512);

    // fused bidirectional scan (4 blocks: dir x batch-half)
    lstm_scan_mfma<<<4, 1024, 0, stream>>>(XPT, WF, HC);

    // classifier -> d_out (32,31,722)
    gemm_bias_kernel<0><<<dim3(31, 12), 256, 0, stream>>>(HC, clsw, clsb, nullptr, out, 992, 722, 512);
}